// Round 7
// baseline (986.320 us; speedup 1.0000x reference)
//
#include <hip/hip_runtime.h>
#include <math.h>

// Problem constants (fixed by the reference)
#define LAYERS 6
#define BB 4
#define NN 23890
#define KTOK 1024
#define DD 256
#define NH 8
#define HDIM 32
#define FFND 1024
#define NCLS 15
#define MROWS (BB*KTOK)   // 4096

typedef __attribute__((ext_vector_type(8))) short bf16x8;
typedef __attribute__((ext_vector_type(4))) float f32x4;

__device__ __forceinline__ unsigned short f2bf(float x) {
    unsigned u = __float_as_uint(x);
    u += 0x7fffu + ((u >> 16) & 1u);          // RNE
    return (unsigned short)(u >> 16);
}

// ---------------------------------------------------------------------------
// Grid-stride float4 copy (out <- query)
// ---------------------------------------------------------------------------
__global__ __launch_bounds__(256) void copy_k(
    const float4* __restrict__ src, float4* __restrict__ dst, int n4)
{
    int i = blockIdx.x * 256 + threadIdx.x;
    const int stride = gridDim.x * 256;
    for (; i < n4; i += stride) dst[i] = src[i];
}

// ---------------------------------------------------------------------------
// Square weight transposes, all 4 weights x 6 layers in one dispatch.
// z = l*4 + sel. W[l][256][256] -> Wt[l][256][256] (bf16, [N][K])
// ---------------------------------------------------------------------------
__global__ __launch_bounds__(256) void transpose_sq_k(
    const float* __restrict__ Wq, const float* __restrict__ Wk,
    const float* __restrict__ Wv, const float* __restrict__ Wo,
    unsigned short* __restrict__ wqt, unsigned short* __restrict__ wkt,
    unsigned short* __restrict__ wvt, unsigned short* __restrict__ wot)
{
    __shared__ float tile[32][33];
    const int l = blockIdx.z >> 2, sel = blockIdx.z & 3;
    const float* W; unsigned short* Wt;
    if (sel == 0)      { W = Wq; Wt = wqt; }
    else if (sel == 1) { W = Wk; Wt = wkt; }
    else if (sel == 2) { W = Wv; Wt = wvt; }
    else               { W = Wo; Wt = wot; }
    const int n0 = blockIdx.x * 32, k0 = blockIdx.y * 32;
    const size_t loff = (size_t)l * DD * DD;
    const int t = threadIdx.x;
    const int r = t >> 3, c = (t & 7) * 4;
    const float4 v = *(const float4*)&W[loff + (size_t)(k0 + r) * DD + n0 + c];
    tile[r][c + 0] = v.x; tile[r][c + 1] = v.y;
    tile[r][c + 2] = v.z; tile[r][c + 3] = v.w;
    __syncthreads();
    ushort4 p;
    p.x = f2bf(tile[c + 0][r]);
    p.y = f2bf(tile[c + 1][r]);
    p.z = f2bf(tile[c + 2][r]);
    p.w = f2bf(tile[c + 3][r]);
    *(ushort4*)&Wt[loff + (size_t)(n0 + r) * DD + k0 + c] = p;
}

// generic version for W1/W2
__global__ __launch_bounds__(256) void transpose_cast_k(
    const float* __restrict__ W, unsigned short* __restrict__ Wt,
    int Kd, int Nd)
{
    __shared__ float tile[32][33];
    const int n0 = blockIdx.x * 32, k0 = blockIdx.y * 32;
    const size_t loff = (size_t)blockIdx.z * Kd * Nd;
    const int t = threadIdx.x;
    const int r = t >> 3, c = (t & 7) * 4;
    const float4 v = *(const float4*)&W[loff + (size_t)(k0 + r) * Nd + n0 + c];
    tile[r][c + 0] = v.x; tile[r][c + 1] = v.y;
    tile[r][c + 2] = v.z; tile[r][c + 3] = v.w;
    __syncthreads();
    ushort4 p;
    p.x = f2bf(tile[c + 0][r]);
    p.y = f2bf(tile[c + 1][r]);
    p.z = f2bf(tile[c + 2][r]);
    p.w = f2bf(tile[c + 3][r]);
    *(ushort4*)&Wt[loff + (size_t)(n0 + r) * Kd + k0 + c] = p;
}

// ---------------------------------------------------------------------------
// Gather + MCSP:  tgt = q*mc (f32+bf16),  qk_bf = bf16(tgt + qpos)
// ---------------------------------------------------------------------------
__global__ __launch_bounds__(256) void gather_k(
    const float* __restrict__ outp, const float* __restrict__ qpos,
    const float* __restrict__ fg, const int* __restrict__ inds,
    const float* __restrict__ Wcls, const float* __restrict__ bcls,
    float* __restrict__ tgt, unsigned short* __restrict__ tgt_bf,
    unsigned short* __restrict__ qk_bf)
{
    const int row = blockIdx.x, t = threadIdx.x;
    const int b = row >> 10;
    const int k = row & 1023;
    const int ind = inds[b * KTOK + k];
    __shared__ float qs[DD];
    __shared__ float sco[NCLS];
    __shared__ float mcsh;
    const size_t src = ((size_t)b * NN + ind) * DD + t;
    const float qv = outp[src];
    qs[t] = qv;
    __syncthreads();
    if (t < NCLS) {
        float s = bcls[t];
        #pragma unroll 8
        for (int d = 0; d < DD; ++d) s = fmaf(qs[d], Wcls[d * NCLS + t], s);
        sco[t] = s;
    }
    __syncthreads();
    if (t == 0) {
        float m = sco[0];
        #pragma unroll
        for (int j = 1; j < NCLS; ++j) m = fmaxf(m, sco[j]);
        mcsh = fg[(size_t)b * NN + ind] / (1.0f + expf(-m));
    }
    __syncthreads();
    const float tv = qv * mcsh;
    const size_t off = (size_t)row * DD + t;
    tgt[off] = tv;
    tgt_bf[off] = f2bf(tv);
    qk_bf[off] = f2bf(tv + qpos[src]);
}

// ---------------------------------------------------------------------------
// MFMA GEMM body (64x64 tile): C = A_bf16 @ Wt_bf16^T + bias
// ---------------------------------------------------------------------------
__device__ __forceinline__ void mgemm_body(
    const unsigned short* __restrict__ A, const unsigned short* __restrict__ Wt,
    const float* __restrict__ bias, float* __restrict__ Cf,
    unsigned short* __restrict__ Cb, unsigned short* __restrict__ VtO,
    int Nsz, int Ksz, bool relu, int bm, int bn)
{
    __shared__ unsigned short As[64 * 32];
    __shared__ unsigned short Bs[64 * 32];
    const int t = threadIdx.x;
    const int lane = t & 63, wave = t >> 6;
    const int ln15 = lane & 15, kg = lane >> 4;
    const int wm = (wave >> 1) * 32, wn = (wave & 1) * 32;
    const int sr = t >> 2, sc = (t & 3) * 8;

    f32x4 acc[2][2];
    #pragma unroll
    for (int i = 0; i < 2; ++i)
        #pragma unroll
        for (int j = 0; j < 2; ++j) acc[i][j] = (f32x4)0.0f;

    for (int k0 = 0; k0 < Ksz; k0 += 32) {
        *(bf16x8*)&As[sr * 32 + sc] =
            *(const bf16x8*)&A[(size_t)(bm + sr) * Ksz + k0 + sc];
        *(bf16x8*)&Bs[sr * 32 + sc] =
            *(const bf16x8*)&Wt[(size_t)(bn + sr) * Ksz + k0 + sc];
        __syncthreads();
        const bf16x8 a0 = *(const bf16x8*)&As[(wm + ln15) * 32 + kg * 8];
        const bf16x8 a1 = *(const bf16x8*)&As[(wm + 16 + ln15) * 32 + kg * 8];
        const bf16x8 b0 = *(const bf16x8*)&Bs[(wn + ln15) * 32 + kg * 8];
        const bf16x8 b1 = *(const bf16x8*)&Bs[(wn + 16 + ln15) * 32 + kg * 8];
        acc[0][0] = __builtin_amdgcn_mfma_f32_16x16x32_bf16(a0, b0, acc[0][0], 0, 0, 0);
        acc[0][1] = __builtin_amdgcn_mfma_f32_16x16x32_bf16(a0, b1, acc[0][1], 0, 0, 0);
        acc[1][0] = __builtin_amdgcn_mfma_f32_16x16x32_bf16(a1, b0, acc[1][0], 0, 0, 0);
        acc[1][1] = __builtin_amdgcn_mfma_f32_16x16x32_bf16(a1, b1, acc[1][1], 0, 0, 0);
        __syncthreads();
    }

    #pragma unroll
    for (int mt = 0; mt < 2; ++mt) {
        #pragma unroll
        for (int nt = 0; nt < 2; ++nt) {
            const int col = bn + wn + nt * 16 + ln15;
            const int r0  = bm + wm + mt * 16 + kg * 4;
            const float bv = bias[col];
            if (VtO) {
                const int bidx = r0 >> 10, tok0 = r0 & 1023;
                const int hh = col >> 5, dd = col & 31;
                ushort4 pk;
                pk.x = f2bf(acc[mt][nt][0] + bv);
                pk.y = f2bf(acc[mt][nt][1] + bv);
                pk.z = f2bf(acc[mt][nt][2] + bv);
                pk.w = f2bf(acc[mt][nt][3] + bv);
                *(ushort4*)&VtO[(((size_t)bidx * NH + hh) * HDIM + dd) * KTOK + tok0] = pk;
            } else {
                #pragma unroll
                for (int j = 0; j < 4; ++j) {
                    float v = acc[mt][nt][j] + bv;
                    if (relu) v = fmaxf(v, 0.0f);
                    const size_t o = (size_t)(r0 + j) * Nsz + col;
                    if (Cf) Cf[o] = v;
                    if (Cb) Cb[o] = f2bf(v);
                }
            }
        }
    }
}

__global__ __launch_bounds__(256) void mgemm_k(
    const unsigned short* __restrict__ A, const unsigned short* __restrict__ Wt,
    const float* __restrict__ bias, float* __restrict__ Cf,
    unsigned short* __restrict__ Cb, int Nsz, int Ksz, int relu)
{
    mgemm_body(A, Wt, bias, Cf, Cb, nullptr, Nsz, Ksz, relu != 0,
               blockIdx.y * 64, blockIdx.x * 64);
}

// Q,K -> bf16 [MROWS][256]; V -> bf16 transposed [B][H][32][KTOK]
__global__ __launch_bounds__(256) void mgemm_qkv_k(
    const unsigned short* __restrict__ qk_bf, const unsigned short* __restrict__ tgt_bf,
    const unsigned short* __restrict__ wqt, const float* __restrict__ bq,
    const unsigned short* __restrict__ wkt, const float* __restrict__ bk,
    const unsigned short* __restrict__ wvt, const float* __restrict__ bv,
    unsigned short* __restrict__ Qbf, unsigned short* __restrict__ Kbf,
    unsigned short* __restrict__ Vtg)
{
    const unsigned short* A; const unsigned short* W; const float* bi;
    unsigned short* Cb = nullptr; unsigned short* Vt = nullptr;
    if (blockIdx.z == 0)      { A = qk_bf;  W = wqt; bi = bq; Cb = Qbf; }
    else if (blockIdx.z == 1) { A = qk_bf;  W = wkt; bi = bk; Cb = Kbf; }
    else                      { A = tgt_bf; W = wvt; bi = bv; Vt = Vtg; }
    mgemm_body(A, W, bi, nullptr, Cb, Vt, DD, DD, false,
               blockIdx.y * 64, blockIdx.x * 64);
}

// ---------------------------------------------------------------------------
// MFMA flash attention (unchanged from r6)
// ---------------------------------------------------------------------------
#define ATT_PSTR 68

__global__ __launch_bounds__(256) void attn_mfma_k(
    const unsigned short* __restrict__ Qbf, const unsigned short* __restrict__ Kbf,
    const unsigned short* __restrict__ Vtg, unsigned short* __restrict__ Ob)
{
    const int qt = blockIdx.x, h = blockIdx.y, b = blockIdx.z;
    const int t = threadIdx.x;
    const int w = t >> 6, lane = t & 63;
    const int ln15 = lane & 15, kg = lane >> 4;

    __shared__ unsigned short Ks[64 * 32];
    __shared__ unsigned short Vts[32 * 64];
    __shared__ float Ps[4][16 * ATT_PSTR];

    const int q0 = qt * 64 + w * 16;
    const bf16x8 aQ = *(const bf16x8*)
        &Qbf[((size_t)(b * KTOK + q0 + ln15)) * DD + h * HDIM + kg * 8];

    f32x4 accO[2];
    accO[0] = (f32x4)0.0f; accO[1] = (f32x4)0.0f;
    float m_i[4], l_i[4];
    #pragma unroll
    for (int i = 0; i < 4; ++i) { m_i[i] = -1e30f; l_i[i] = 0.0f; }
    const float scale = 0.17677669529663687f;

    const int krow = t >> 2, kd0 = (t & 3) * 8;
    const int vd = t >> 3, vt0 = (t & 7) * 8;

    for (int kt = 0; kt < 16; ++kt) {
        __syncthreads();
        *(bf16x8*)&Ks[krow * 32 + kd0] = *(const bf16x8*)
            &Kbf[((size_t)(b * KTOK + kt * 64 + krow)) * DD + h * HDIM + kd0];
        *(bf16x8*)&Vts[vd * 64 + vt0] = *(const bf16x8*)
            &Vtg[(((size_t)b * NH + h) * HDIM + vd) * KTOK + kt * 64 + vt0];
        __syncthreads();

        f32x4 s[4];
        #pragma unroll
        for (int st = 0; st < 4; ++st) {
            const bf16x8 bK = *(const bf16x8*)&Ks[(st * 16 + ln15) * 32 + kg * 8];
            s[st] = __builtin_amdgcn_mfma_f32_16x16x32_bf16(aQ, bK, (f32x4)0.0f, 0, 0, 0);
        }
        #pragma unroll
        for (int r = 0; r < 4; ++r) {
            float v0 = s[0][r] * scale, v1 = s[1][r] * scale;
            float v2 = s[2][r] * scale, v3 = s[3][r] * scale;
            float rm = fmaxf(fmaxf(v0, v1), fmaxf(v2, v3));
            rm = fmaxf(rm, __shfl_xor(rm, 1));
            rm = fmaxf(rm, __shfl_xor(rm, 2));
            rm = fmaxf(rm, __shfl_xor(rm, 4));
            rm = fmaxf(rm, __shfl_xor(rm, 8));
            const float mnew = fmaxf(m_i[r], rm);
            const float alpha = __expf(m_i[r] - mnew);
            v0 = __expf(v0 - mnew); v1 = __expf(v1 - mnew);
            v2 = __expf(v2 - mnew); v3 = __expf(v3 - mnew);
            float ls = v0 + v1 + v2 + v3;
            ls += __shfl_xor(ls, 1); ls += __shfl_xor(ls, 2);
            ls += __shfl_xor(ls, 4); ls += __shfl_xor(ls, 8);
            l_i[r] = l_i[r] * alpha + ls;
            m_i[r] = mnew;
            accO[0][r] *= alpha; accO[1][r] *= alpha;
            const int pr = (kg * 4 + r) * ATT_PSTR + ln15;
            Ps[w][pr +  0] = v0;
            Ps[w][pr + 16] = v1;
            Ps[w][pr + 32] = v2;
            Ps[w][pr + 48] = v3;
        }
        #pragma unroll
        for (int kc = 0; kc < 2; ++kc) {
            const float* prow = &Ps[w][ln15 * ATT_PSTR + kc * 32 + kg * 8];
            const float4 pa = *(const float4*)prow;
            const float4 pb = *(const float4*)(prow + 4);
            bf16x8 aP;
            aP[0] = (short)f2bf(pa.x); aP[1] = (short)f2bf(pa.y);
            aP[2] = (short)f2bf(pa.z); aP[3] = (short)f2bf(pa.w);
            aP[4] = (short)f2bf(pb.x); aP[5] = (short)f2bf(pb.y);
            aP[6] = (short)f2bf(pb.z); aP[7] = (short)f2bf(pb.w);
            #pragma unroll
            for (int dt = 0; dt < 2; ++dt) {
                const bf16x8 bV = *(const bf16x8*)
                    &Vts[(dt * 16 + ln15) * 64 + kc * 32 + kg * 8];
                accO[dt] = __builtin_amdgcn_mfma_f32_16x16x32_bf16(aP, bV, accO[dt], 0, 0, 0);
            }
        }
    }

    #pragma unroll
    for (int dt = 0; dt < 2; ++dt)
        #pragma unroll
        for (int r = 0; r < 4; ++r) {
            const float v = accO[dt][r] / l_i[r];
            Ob[((size_t)(b * KTOK + q0 + kg * 4 + r)) * DD + h * HDIM + dt * 16 + ln15]
                = f2bf(v);
        }
}

// ---------------------------------------------------------------------------
// Wide fused GEMM + residual + LayerNorm body.
// Block: 32 rows x 256 cols (full row width). 4 waves; wave w owns cols
// [w*64, w*64+64). acc[2][4] of 16x16 D-tiles.
// After GEMM: v = acc + bias + res;  LN over the 256 cols; then either
// write x/x_bf (mode 0) or ragged-scatter to out (mode 1).
// ---------------------------------------------------------------------------
__device__ __forceinline__ void wide_gemm_ln(
    const unsigned short* __restrict__ A, const unsigned short* __restrict__ Wt,
    const float* __restrict__ bias, const float* __restrict__ res,
    const float* __restrict__ g, const float* __restrict__ be,
    int Ksz, int bm,
    // mode 0 outputs:
    float* __restrict__ xo, unsigned short* __restrict__ xo_bf,
    // mode 1 outputs:
    const int* __restrict__ inds, const int* __restrict__ focus,
    float* __restrict__ outp)
{
    __shared__ unsigned short As[32 * 32];     // 2 KB
    __shared__ unsigned short Bs[256 * 32];    // 16 KB
    __shared__ float redS[4][32], redQ[4][32];
    __shared__ float mu_s[32], rs_s[32];

    const int t = threadIdx.x;
    const int lane = t & 63, w = t >> 6;
    const int ln15 = lane & 15, kg = lane >> 4;
    const int wn = w * 64;
    const int sr4 = t >> 2, sc4 = (t & 3) * 8;

    f32x4 acc[2][4];
    #pragma unroll
    for (int i = 0; i < 2; ++i)
        #pragma unroll
        for (int j = 0; j < 4; ++j) acc[i][j] = (f32x4)0.0f;

    for (int k0 = 0; k0 < Ksz; k0 += 32) {
        if (t < 128)
            *(bf16x8*)&As[(t >> 2) * 32 + (t & 3) * 8] =
                *(const bf16x8*)&A[(size_t)(bm + (t >> 2)) * Ksz + k0 + (t & 3) * 8];
        #pragma unroll
        for (int rep = 0; rep < 4; ++rep) {
            const int rrow = rep * 64 + sr4;
            *(bf16x8*)&Bs[rrow * 32 + sc4] =
                *(const bf16x8*)&Wt[(size_t)rrow * Ksz + k0 + sc4];
        }
        __syncthreads();
        const bf16x8 a0 = *(const bf16x8*)&As[ln15 * 32 + kg * 8];
        const bf16x8 a1 = *(const bf16x8*)&As[(16 + ln15) * 32 + kg * 8];
        #pragma unroll
        for (int nt = 0; nt < 4; ++nt) {
            const bf16x8 bf = *(const bf16x8*)&Bs[(wn + nt * 16 + ln15) * 32 + kg * 8];
            acc[0][nt] = __builtin_amdgcn_mfma_f32_16x16x32_bf16(a0, bf, acc[0][nt], 0, 0, 0);
            acc[1][nt] = __builtin_amdgcn_mfma_f32_16x16x32_bf16(a1, bf, acc[1][nt], 0, 0, 0);
        }
        __syncthreads();
    }

    // bias + residual; accumulate row partial sums
    float s1[2][4], s2[2][4];
    #pragma unroll
    for (int mt = 0; mt < 2; ++mt)
        #pragma unroll
        for (int j = 0; j < 4; ++j) { s1[mt][j] = 0.0f; s2[mt][j] = 0.0f; }

    #pragma unroll
    for (int mt = 0; mt < 2; ++mt) {
        #pragma unroll
        for (int nt = 0; nt < 4; ++nt) {
            const int col = wn + nt * 16 + ln15;
            const float bv = bias[col];
            #pragma unroll
            for (int j = 0; j < 4; ++j) {
                const int rl = mt * 16 + kg * 4 + j;
                float v = acc[mt][nt][j] + bv + res[(size_t)(bm + rl) * DD + col];
                acc[mt][nt][j] = v;
                s1[mt][j] += v;
                s2[mt][j] += v * v;
            }
        }
    }
    // reduce across the 16 lanes of each kg group
    #pragma unroll
    for (int mt = 0; mt < 2; ++mt)
        #pragma unroll
        for (int j = 0; j < 4; ++j) {
            float a = s1[mt][j], q = s2[mt][j];
            a += __shfl_xor(a, 1); q += __shfl_xor(q, 1);
            a += __shfl_xor(a, 2); q += __shfl_xor(q, 2);
            a += __shfl_xor(a, 4); q += __shfl_xor(q, 4);
            a += __shfl_xor(a, 8); q += __shfl_xor(q, 8);
            if (ln15 == 0) {
                const int rl = mt * 16 + kg * 4 + j;
                redS[w][rl] = a; redQ[w][rl] = q;
            }
        }
    __syncthreads();
    if (t < 32) {
        const float a = redS[0][t] + redS[1][t] + redS[2][t] + redS[3][t];
        const float q = redQ[0][t] + redQ[1][t] + redQ[2][t] + redQ[3][t];
        const float mu = a * (1.0f / DD);
        const float var = q * (1.0f / DD) - mu * mu;
        mu_s[t] = mu;
        rs_s[t] = rsqrtf(var + 1e-5f);
    }
    __syncthreads();

    if (outp == nullptr) {
        #pragma unroll
        for (int mt = 0; mt < 2; ++mt)
            #pragma unroll
            for (int nt = 0; nt < 4; ++nt) {
                const int col = wn + nt * 16 + ln15;
                const float gv = g[col], bev = be[col];
                #pragma unroll
                for (int j = 0; j < 4; ++j) {
                    const int rl = mt * 16 + kg * 4 + j;
                    const float r = (acc[mt][nt][j] - mu_s[rl]) * rs_s[rl] * gv + bev;
                    const size_t o = (size_t)(bm + rl) * DD + col;
                    xo[o] = r;
                    xo_bf[o] = f2bf(r);
                }
            }
    } else {
        const int bidx = bm >> 10;            // 32-row block lies in one batch
        const int focusb = focus[bidx];
        #pragma unroll
        for (int mt = 0; mt < 2; ++mt)
            #pragma unroll
            for (int j = 0; j < 4; ++j) {
                const int rl = mt * 16 + kg * 4 + j;
                const int kk = (bm & 1023) + rl;
                if (kk >= focusb) continue;
                const int ind = inds[bidx * KTOK + kk];
                float* orow = &outp[((size_t)bidx * NN + ind) * DD];
                #pragma unroll
                for (int nt = 0; nt < 4; ++nt) {
                    const int col = wn + nt * 16 + ln15;
                    orow[col] = (acc[mt][nt][j] - mu_s[rl]) * rs_s[rl] * g[col] + be[col];
                }
            }
    }
}

__global__ __launch_bounds__(256) void oproj_ln_k(
    const unsigned short* __restrict__ attno_bf, const unsigned short* __restrict__ wot,
    const float* __restrict__ bo, const float* __restrict__ tgt,
    const float* __restrict__ g1, const float* __restrict__ be1,
    float* __restrict__ x, unsigned short* __restrict__ x_bf)
{
    wide_gemm_ln(attno_bf, wot, bo, tgt, g1, be1, DD, blockIdx.x * 32,
                 x, x_bf, nullptr, nullptr, nullptr);
}

__global__ __launch_bounds__(256) void ffn2_ln_scatter_k(
    const unsigned short* __restrict__ ff1_bf, const unsigned short* __restrict__ w2t,
    const float* __restrict__ b2, const float* __restrict__ x,
    const float* __restrict__ g2, const float* __restrict__ be2,
    const int* __restrict__ inds, const int* __restrict__ focus,
    float* __restrict__ outp)
{
    wide_gemm_ln(ff1_bf, w2t, b2, x, g2, be2, FFND, blockIdx.x * 32,
                 nullptr, nullptr, inds, focus, outp);
}

// ---------------------------------------------------------------------------
extern "C" void kernel_launch(void* const* d_in, const int* in_sizes, int n_in,
                              void* d_out, int out_size, void* d_ws, size_t ws_size,
                              hipStream_t stream)
{
    const float* query = (const float*)d_in[0];
    const float* qpos  = (const float*)d_in[1];
    const float* fg    = (const float*)d_in[6];
    const int*   focus = (const int*)d_in[7];
    const int*   finds = (const int*)d_in[8];
    const float* Wq = (const float*)d_in[9];  const float* bq = (const float*)d_in[10];
    const float* Wk = (const float*)d_in[11]; const float* bk = (const float*)d_in[12];
    const float* Wv = (const float*)d_in[13]; const float* bv = (const float*)d_in[14];
    const float* Wo = (const float*)d_in[15]; const float* bo = (const float*)d_in[16];
    const float* g1 = (const float*)d_in[17]; const float* be1 = (const float*)d_in[18];
    const float* W1 = (const float*)d_in[19]; const float* b1 = (const float*)d_in[20];
    const float* W2 = (const float*)d_in[21]; const float* b2 = (const float*)d_in[22];
    const float* g2 = (const float*)d_in[23]; const float* be2 = (const float*)d_in[24];
    const float* Wcls = (const float*)d_in[25]; const float* bcls = (const float*)d_in[26];
    float* out = (float*)d_out;

    // ---- workspace layout -------------------------------------------------
    char* p = (char*)d_ws;
    const size_t MD4 = (size_t)MROWS * DD * 4;
    const size_t MD2 = (size_t)MROWS * DD * 2;
    float* tgt  = (float*)p;  p += MD4;
    float* x    = (float*)p;  p += MD4;
    unsigned short* tgt_bf   = (unsigned short*)p;  p += MD2;
    unsigned short* qk_bf    = (unsigned short*)p;  p += MD2;
    unsigned short* attno_bf = (unsigned short*)p;  p += MD2;
    unsigned short* x_bf     = (unsigned short*)p;  p += MD2;
    unsigned short* Qbf      = (unsigned short*)p;  p += MD2;
    unsigned short* Kbf      = (unsigned short*)p;  p += MD2;
    unsigned short* Vtg      = (unsigned short*)p;  p += MD2;
    unsigned short* ff1_bf   = (unsigned short*)p;  p += (size_t)MROWS * FFND * 2;
    const size_t WSQ = (size_t)LAYERS * DD * DD;
    const size_t WFF = (size_t)LAYERS * DD * FFND;
    unsigned short* wqt = (unsigned short*)p;  p += WSQ * 2;
    unsigned short* wkt = (unsigned short*)p;  p += WSQ * 2;
    unsigned short* wvt = (unsigned short*)p;  p += WSQ * 2;
    unsigned short* wot = (unsigned short*)p;  p += WSQ * 2;
    unsigned short* w1t = (unsigned short*)p;  p += WFF * 2;
    unsigned short* w2t = (unsigned short*)p;  p += WFF * 2;

    // one-time weight transposes to bf16 Wt[N][K]
    transpose_sq_k<<<dim3(DD / 32, DD / 32, LAYERS * 4), 256, 0, stream>>>(
        Wq, Wk, Wv, Wo, wqt, wkt, wvt, wot);
    transpose_cast_k<<<dim3(FFND / 32, DD / 32, LAYERS), 256, 0, stream>>>(W1, w1t, DD, FFND);
    transpose_cast_k<<<dim3(DD / 32, FFND / 32, LAYERS), 256, 0, stream>>>(W2, w2t, FFND, DD);

    // output starts as query
    copy_k<<<2048, 256, 0, stream>>>((const float4*)query, (float4*)out,
                                     (int)((size_t)BB * NN * DD / 4));

    for (int l = 0; l < LAYERS; ++l) {
        const int* inds = finds + (size_t)l * BB * KTOK;
        gather_k<<<MROWS, 256, 0, stream>>>(out, qpos, fg, inds, Wcls, bcls,
                                            tgt, tgt_bf, qk_bf);
        mgemm_qkv_k<<<dim3(DD / 64, MROWS / 64, 3), 256, 0, stream>>>(
            qk_bf, tgt_bf,
            wqt + (size_t)l * DD * DD, bq + (size_t)l * DD,
            wkt + (size_t)l * DD * DD, bk + (size_t)l * DD,
            wvt + (size_t)l * DD * DD, bv + (size_t)l * DD,
            Qbf, Kbf, Vtg);
        attn_mfma_k<<<dim3(KTOK / 64, NH, BB), 256, 0, stream>>>(Qbf, Kbf, Vtg, attno_bf);
        oproj_ln_k<<<MROWS / 32, 256, 0, stream>>>(
            attno_bf, wot + (size_t)l * DD * DD, bo + (size_t)l * DD,
            tgt, g1 + (size_t)l * DD, be1 + (size_t)l * DD, x, x_bf);
        mgemm_k<<<dim3(FFND / 64, MROWS / 64), 256, 0, stream>>>(
            x_bf, w1t + (size_t)l * DD * FFND, b1 + (size_t)l * FFND,
            nullptr, ff1_bf, FFND, DD, 1);
        ffn2_ln_scatter_k<<<MROWS / 32, 256, 0, stream>>>(
            ff1_bf, w2t + (size_t)l * DD * FFND, b2 + (size_t)l * DD,
            x, g2 + (size_t)l * DD, be2 + (size_t)l * DD, inds, focus, out);
    }
    (void)in_sizes; (void)n_in; (void)out_size; (void)ws_size;
}